// Round 1
// baseline (1734.778 us; speedup 1.0000x reference)
//
#include <hip/hip_runtime.h>

#define THREADS 256

__device__ __forceinline__ unsigned fenc(float x) {
    unsigned u = __float_as_uint(x);
    return (u & 0x80000000u) ? ~u : (u | 0x80000000u);
}
__device__ __forceinline__ float fdec(unsigned u) {
    return (u & 0x80000000u) ? __uint_as_float(u & 0x7fffffffu) : __uint_as_float(~u);
}
__device__ __forceinline__ float lrelu(float x) { return x > 0.f ? x : 0.2f * x; }

// ---------------- GEMM: Hout[N,M] = X[N,K] @ W[K,M] ----------------
template <int K, int M>
__global__ void gemm_kernel(const float* __restrict__ X, const float* __restrict__ W,
                            float* __restrict__ Hout, int nNodes) {
    constexpr int NB = 16;                 // nodes per block
    constexpr int NL = THREADS / M;        // node lanes
    constexpr int PER = NB / NL;           // nodes per thread
    __shared__ float xs[NB][K];

    int node0 = blockIdx.x * NB;
    for (int i = threadIdx.x; i < NB * K; i += THREADS) {
        int nn = i / K, kk = i % K;
        int n = node0 + nn;
        xs[nn][kk] = (n < nNodes) ? X[(size_t)n * K + kk] : 0.f;
    }
    __syncthreads();

    int col = threadIdx.x % M;
    int nl = threadIdx.x / M;
    float acc[PER];
#pragma unroll
    for (int i = 0; i < PER; ++i) acc[i] = 0.f;

    for (int k = 0; k < K; ++k) {
        float w = W[k * M + col];
#pragma unroll
        for (int i = 0; i < PER; ++i) acc[i] += xs[nl + i * NL][k] * w;
    }
#pragma unroll
    for (int i = 0; i < PER; ++i) {
        int n = node0 + nl + i * NL;
        if (n < nNodes) Hout[(size_t)n * M + col] = acc[i];
    }
}

// ---------------- per-node attention logits ----------------
template <int M, int H, int C>
__global__ void alpha_kernel(const float* __restrict__ Hf, const float* __restrict__ a_src,
                             const float* __restrict__ a_dst, float* __restrict__ asb,
                             float* __restrict__ adb, int nNodes) {
    int idx = blockIdx.x * THREADS + threadIdx.x;
    if (idx >= nNodes * H) return;
    int n = idx / H, h = idx % H;
    const float* hp = Hf + (size_t)n * M + h * C;
    float s = 0.f, d = 0.f;
#pragma unroll
    for (int c = 0; c < C; ++c) {
        float v = hp[c];
        s += v * a_src[h * C + c];
        d += v * a_dst[h * C + c];
    }
    asb[idx] = s;
    adb[idx] = d;
}

// ---------------- init m with self-loop e ----------------
template <int H>
__global__ void init_max(const float* __restrict__ asb, const float* __restrict__ adb,
                         unsigned* __restrict__ m, int nNodes) {
    int idx = blockIdx.x * THREADS + threadIdx.x;
    if (idx >= nNodes * H) return;
    m[idx] = fenc(lrelu(asb[idx] + adb[idx]));
}

// ---------------- pass 1: e per edge + segment max ----------------
template <int H>
__global__ void edge_max(const int* __restrict__ src, const int* __restrict__ dst,
                         const float* __restrict__ asb, const float* __restrict__ adb,
                         float* __restrict__ ebuf, unsigned* __restrict__ m, int nE) {
    int e = blockIdx.x * THREADS + threadIdx.x;
    if (e >= nE) return;
    int s = src[e], d = dst[e];
#pragma unroll
    for (int h = 0; h < H; ++h) {
        float v = lrelu(asb[s * H + h] + adb[d * H + h]);
        ebuf[(size_t)e * H + h] = v;
        atomicMax(&m[d * H + h], fenc(v));
    }
}

// ---------------- init denom with self-loop exp ----------------
template <int H>
__global__ void init_denom(const float* __restrict__ asb, const float* __restrict__ adb,
                           const unsigned* __restrict__ m, float* __restrict__ denom,
                           int nNodes) {
    int idx = blockIdx.x * THREADS + threadIdx.x;
    if (idx >= nNodes * H) return;
    float e = lrelu(asb[idx] + adb[idx]);
    denom[idx] = expf(e - fdec(m[idx]));
}

// ---------------- pass 2: ex per edge + segment sum ----------------
template <int H>
__global__ void edge_sum(const int* __restrict__ dst, float* __restrict__ ebuf,
                         const unsigned* __restrict__ m, float* __restrict__ denom, int nE) {
    int e = blockIdx.x * THREADS + threadIdx.x;
    if (e >= nE) return;
    int d = dst[e];
#pragma unroll
    for (int h = 0; h < H; ++h) {
        float ex = expf(ebuf[(size_t)e * H + h] - fdec(m[d * H + h]));
        ebuf[(size_t)e * H + h] = ex;
        atomicAdd(&denom[d * H + h], ex);
    }
}

// ---------------- init out with bias + self-loop message ----------------
template <int M, int H, int C>
__global__ void init_out(const float* __restrict__ Hf, const float* __restrict__ asb,
                         const float* __restrict__ adb, const unsigned* __restrict__ m,
                         const float* __restrict__ denom, const float* __restrict__ bias,
                         float* __restrict__ out, int nNodes) {
    int idx = blockIdx.x * THREADS + threadIdx.x;
    if (idx >= nNodes * M) return;
    int n = idx / M, cc = idx % M;
    int h = cc / C;
    float e = lrelu(asb[n * H + h] + adb[n * H + h]);
    float ex = expf(e - fdec(m[n * H + h]));
    float alpha = ex / (denom[n * H + h] + 1e-16f);
    out[idx] = bias[cc] + Hf[idx] * alpha;
}

// ---------------- pass 3: weighted message aggregation ----------------
template <int M, int H, int C>
__global__ void edge_aggr(const int* __restrict__ src, const int* __restrict__ dst,
                          const float* __restrict__ Hf, const float* __restrict__ ebuf,
                          const float* __restrict__ denom, float* __restrict__ out, int nE) {
    int idx = blockIdx.x * THREADS + threadIdx.x;
    if (idx >= nE * M) return;
    int e = idx / M, cc = idx % M;
    int h = cc / C;
    int s = src[e], d = dst[e];
    float alpha = ebuf[(size_t)e * H + h] / (denom[d * H + h] + 1e-16f);
    atomicAdd(&out[(size_t)d * M + cc], Hf[(size_t)s * M + cc] * alpha);
}

// ---------------- ELU in place ----------------
__global__ void elu_kernel(float* __restrict__ buf, int n) {
    int idx = blockIdx.x * THREADS + threadIdx.x;
    if (idx >= n) return;
    float v = buf[idx];
    buf[idx] = v > 0.f ? v : expm1f(v);
}

// ---------------- mean pool ----------------
__global__ void pool_sum(const float* __restrict__ act, const int* __restrict__ batch,
                         float* __restrict__ out, float* __restrict__ cnt, int nNodes) {
    int idx = blockIdx.x * THREADS + threadIdx.x;
    if (idx >= nNodes * 32) return;
    int n = idx >> 5, c = idx & 31;
    int g = batch[n];
    atomicAdd(&out[g * 32 + c], act[(size_t)n * 32 + c]);
    if (c == 0) atomicAdd(&cnt[g], 1.0f);
}

__global__ void pool_div(float* __restrict__ out, const float* __restrict__ cnt, int G) {
    int idx = blockIdx.x * THREADS + threadIdx.x;
    if (idx >= G * 32) return;
    out[idx] /= fmaxf(cnt[idx >> 5], 1.0f);
}

// ---------------- host-side layer driver ----------------
template <int K, int M, int H, int C>
static void run_layer(const float* X, const float* W, const float* a_s, const float* a_d,
                      const float* bias, float* Hbuf, float* Out, float* asb, float* adb,
                      unsigned* mb, float* denom, float* ebuf, const int* srcp,
                      const int* dstp, int N, int E, hipStream_t stream) {
    dim3 blk(THREADS);
    gemm_kernel<K, M><<<(N + 15) / 16, blk, 0, stream>>>(X, W, Hbuf, N);
    alpha_kernel<M, H, C><<<(N * H + THREADS - 1) / THREADS, blk, 0, stream>>>(Hbuf, a_s, a_d,
                                                                               asb, adb, N);
    init_max<H><<<(N * H + THREADS - 1) / THREADS, blk, 0, stream>>>(asb, adb, mb, N);
    edge_max<H><<<(E + THREADS - 1) / THREADS, blk, 0, stream>>>(srcp, dstp, asb, adb, ebuf, mb,
                                                                 E);
    init_denom<H><<<(N * H + THREADS - 1) / THREADS, blk, 0, stream>>>(asb, adb, mb, denom, N);
    edge_sum<H><<<(E + THREADS - 1) / THREADS, blk, 0, stream>>>(dstp, ebuf, mb, denom, E);
    init_out<M, H, C><<<(N * M + THREADS - 1) / THREADS, blk, 0, stream>>>(Hbuf, asb, adb, mb,
                                                                           denom, bias, Out, N);
    long long tot = (long long)E * M;
    edge_aggr<M, H, C><<<(int)((tot + THREADS - 1) / THREADS), blk, 0, stream>>>(
        srcp, dstp, Hbuf, ebuf, denom, Out, E);
    elu_kernel<<<(N * M + THREADS - 1) / THREADS, blk, 0, stream>>>(Out, N * M);
}

extern "C" void kernel_launch(void* const* d_in, const int* in_sizes, int n_in, void* d_out,
                              int out_size, void* d_ws, size_t ws_size, hipStream_t stream) {
    const float* x = (const float*)d_in[0];
    const int* ei = (const int*)d_in[1];
    const int* batch = (const int*)d_in[2];
    const float* W1 = (const float*)d_in[3];
    const float* as1 = (const float*)d_in[4];
    const float* ad1 = (const float*)d_in[5];
    const float* b1 = (const float*)d_in[6];
    const float* W2 = (const float*)d_in[7];
    const float* as2 = (const float*)d_in[8];
    const float* ad2 = (const float*)d_in[9];
    const float* b2 = (const float*)d_in[10];
    const float* W3 = (const float*)d_in[11];
    const float* as3 = (const float*)d_in[12];
    const float* ad3 = (const float*)d_in[13];
    const float* b3 = (const float*)d_in[14];

    const int N = in_sizes[0] / 128;
    const int E = in_sizes[1] / 2;
    const int G = out_size / 32;
    const int* srcp = ei;
    const int* dstp = ei + E;

    char* ws = (char*)d_ws;
    float* A = (float*)ws;                                  // N*128
    float* B = (float*)(ws + (size_t)N * 128 * 4);          // N*128
    float* asb = (float*)(ws + (size_t)N * 128 * 4 * 2);    // N*4
    float* adb = asb + (size_t)N * 4;                       // N*4
    unsigned* mb = (unsigned*)(adb + (size_t)N * 4);        // N*4
    float* denom = (float*)(mb + (size_t)N * 4);            // N*4
    float* ebuf = denom + (size_t)N * 4;                    // E*4
    float* cnt = ebuf + (size_t)E * 4;                      // G

    hipMemsetAsync(d_out, 0, (size_t)G * 32 * 4, stream);
    hipMemsetAsync(cnt, 0, (size_t)G * 4, stream);

    // Layer 1: x[N,128] -> B[N,128]
    run_layer<128, 128, 4, 32>(x, W1, as1, ad1, b1, A, B, asb, adb, mb, denom, ebuf, srcp, dstp,
                               N, E, stream);
    // Layer 2: B[N,128] -> B[N,128]
    run_layer<128, 128, 4, 32>(B, W2, as2, ad2, b2, A, B, asb, adb, mb, denom, ebuf, srcp, dstp,
                               N, E, stream);
    // Layer 3: B[N,128] -> B[N,32]
    run_layer<128, 32, 1, 32>(B, W3, as3, ad3, b3, A, B, asb, adb, mb, denom, ebuf, srcp, dstp,
                              N, E, stream);

    dim3 blk(THREADS);
    pool_sum<<<(N * 32 + THREADS - 1) / THREADS, blk, 0, stream>>>(B, batch, (float*)d_out, cnt,
                                                                   N);
    pool_div<<<(G * 32 + THREADS - 1) / THREADS, blk, 0, stream>>>((float*)d_out, cnt, G);
}

// Round 2
// 561.420 us; speedup vs baseline: 3.0900x; 3.0900x over previous
//
#include <hip/hip_runtime.h>

#define THREADS 256

__device__ __forceinline__ float lrelu(float x) { return x > 0.f ? x : 0.2f * x; }
__device__ __forceinline__ float elu(float x) { return x > 0.f ? x : expm1f(x); }

// ---------------- GEMM: Hout[N,M] = X[N,K] @ W[K,M] ----------------
template <int K, int M>
__global__ void gemm_kernel(const float* __restrict__ X, const float* __restrict__ W,
                            float* __restrict__ Hout, int nNodes) {
    constexpr int NB = 16;                 // nodes per block
    constexpr int NL = THREADS / M;        // node lanes
    constexpr int PER = NB / NL;           // nodes per thread
    __shared__ float xs[NB][K];

    int node0 = blockIdx.x * NB;
    for (int i = threadIdx.x; i < NB * K; i += THREADS) {
        int nn = i / K, kk = i % K;
        int n = node0 + nn;
        xs[nn][kk] = (n < nNodes) ? X[(size_t)n * K + kk] : 0.f;
    }
    __syncthreads();

    int col = threadIdx.x % M;
    int nl = threadIdx.x / M;
    float acc[PER];
#pragma unroll
    for (int i = 0; i < PER; ++i) acc[i] = 0.f;

    for (int k = 0; k < K; ++k) {
        float w = W[k * M + col];
#pragma unroll
        for (int i = 0; i < PER; ++i) acc[i] += xs[nl + i * NL][k] * w;
    }
#pragma unroll
    for (int i = 0; i < PER; ++i) {
        int n = node0 + nl + i * NL;
        if (n < nNodes) Hout[(size_t)n * M + col] = acc[i];
    }
}

// ---------------- per-node attention logits ----------------
template <int M, int H, int C>
__global__ void alpha_kernel(const float* __restrict__ Hf, const float* __restrict__ a_src,
                             const float* __restrict__ a_dst, float* __restrict__ asb,
                             float* __restrict__ adb, int nNodes) {
    int idx = blockIdx.x * THREADS + threadIdx.x;
    if (idx >= nNodes * H) return;
    int n = idx / H, h = idx % H;
    const float* hp = Hf + (size_t)n * M + h * C;
    float s = 0.f, d = 0.f;
#pragma unroll
    for (int c = 0; c < C; ++c) {
        float v = hp[c];
        s += v * a_src[h * C + c];
        d += v * a_dst[h * C + c];
    }
    asb[idx] = s;
    adb[idx] = d;
}

// ---------------- CSR build ----------------
__global__ void hist_kernel(const int* __restrict__ dst, int* __restrict__ deg, int nE) {
    int e = blockIdx.x * THREADS + threadIdx.x;
    if (e < nE) atomicAdd(&deg[dst[e]], 1);
}

__global__ void scan1_kernel(const int* __restrict__ deg, int* __restrict__ partial,
                             int* __restrict__ bsum, int n) {
    __shared__ int sh[THREADS];
    int i = blockIdx.x * THREADS + threadIdx.x;
    int v = (i < n) ? deg[i] : 0;
    sh[threadIdx.x] = v;
    __syncthreads();
    for (int off = 1; off < THREADS; off <<= 1) {
        int t = (threadIdx.x >= off) ? sh[threadIdx.x - off] : 0;
        __syncthreads();
        sh[threadIdx.x] += t;
        __syncthreads();
    }
    if (i < n) partial[i] = sh[threadIdx.x];  // inclusive scan within block
    if (threadIdx.x == THREADS - 1) bsum[blockIdx.x] = sh[THREADS - 1];
}

__global__ void scan2_kernel(int* __restrict__ bsum, int nblk) {
    __shared__ int sh[THREADS];
    int v = (threadIdx.x < nblk) ? bsum[threadIdx.x] : 0;
    sh[threadIdx.x] = v;
    __syncthreads();
    for (int off = 1; off < THREADS; off <<= 1) {
        int t = (threadIdx.x >= off) ? sh[threadIdx.x - off] : 0;
        __syncthreads();
        sh[threadIdx.x] += t;
        __syncthreads();
    }
    if (threadIdx.x < nblk)
        bsum[threadIdx.x] = (threadIdx.x == 0) ? 0 : sh[threadIdx.x - 1];  // exclusive
}

__global__ void scan3_kernel(const int* __restrict__ partial, const int* __restrict__ bsum,
                             int* __restrict__ rowptr, int* __restrict__ cursor, int n) {
    int i = blockIdx.x * THREADS + threadIdx.x;
    if (i < n) {
        rowptr[i + 1] = partial[i] + bsum[blockIdx.x];
        cursor[i] = 0;
    }
    if (i == 0) rowptr[0] = 0;
}

__global__ void scatter_kernel(const int* __restrict__ src, const int* __restrict__ dst,
                               const int* __restrict__ rowptr, int* __restrict__ cursor,
                               int* __restrict__ csr, int nE) {
    int e = blockIdx.x * THREADS + threadIdx.x;
    if (e >= nE) return;
    int d = dst[e];
    int p = atomicAdd(&cursor[d], 1);
    csr[rowptr[d] + p] = src[e];
}

// ---------------- fused per-node softmax + aggregation + ELU ----------------
template <int M, int H, int C>
__global__ void node_aggr(const float* __restrict__ Hf, const float* __restrict__ asb,
                          const float* __restrict__ adb, const int* __restrict__ rowptr,
                          const int* __restrict__ csr, const float* __restrict__ bias,
                          float* __restrict__ out, int nNodes) {
    constexpr int CPL = (M + 63) / 64;  // channels per lane (M=128 -> 2, M=32 -> 1)
    int wid = threadIdx.x >> 6;
    int lane = threadIdx.x & 63;
    int node = blockIdx.x * (THREADS / 64) + wid;
    if (node >= nNodes) return;

    int e0 = rowptr[node];
    int deg = rowptr[node + 1] - e0;

    float adn[H], eself[H], m[H];
#pragma unroll
    for (int h = 0; h < H; ++h) {
        adn[h] = adb[node * H + h];
        eself[h] = lrelu(asb[node * H + h] + adn[h]);
        m[h] = eself[h];
    }

    // phase 1: segment max (lane-parallel over edges)
    for (int i = lane; i < deg; i += 64) {
        int s = csr[e0 + i];
#pragma unroll
        for (int h = 0; h < H; ++h) m[h] = fmaxf(m[h], lrelu(asb[s * H + h] + adn[h]));
    }
#pragma unroll
    for (int off = 32; off > 0; off >>= 1)
#pragma unroll
        for (int h = 0; h < H; ++h) m[h] = fmaxf(m[h], __shfl_xor(m[h], off));

    // phase 2: denom
    float den[H];
#pragma unroll
    for (int h = 0; h < H; ++h) den[h] = 0.f;
    for (int i = lane; i < deg; i += 64) {
        int s = csr[e0 + i];
#pragma unroll
        for (int h = 0; h < H; ++h) den[h] += expf(lrelu(asb[s * H + h] + adn[h]) - m[h]);
    }
#pragma unroll
    for (int off = 32; off > 0; off >>= 1)
#pragma unroll
        for (int h = 0; h < H; ++h) den[h] += __shfl_xor(den[h], off);

    float inv[H];
#pragma unroll
    for (int h = 0; h < H; ++h) {
        den[h] += expf(eself[h] - m[h]);
        inv[h] = 1.f / (den[h] + 1e-16f);
    }

    // phase 3: weighted aggregation, CPL channels per lane
    int ch = lane * CPL;
    bool active = ch < M;
    if (ch > M - CPL) ch = M - CPL;  // clamp inactive lanes to safe addresses
    int myh = ch / C;

    // extract per-head scalars with compile-time-unrolled selects (avoid scratch)
    float mm = m[0], ii = inv[0], aa = adn[0], es = eself[0];
#pragma unroll
    for (int h = 1; h < H; ++h)
        if (myh == h) { mm = m[h]; ii = inv[h]; aa = adn[h]; es = eself[h]; }

    float acc[CPL];
    float alSelf = expf(es - mm) * ii;
#pragma unroll
    for (int c = 0; c < CPL; ++c) acc[c] = alSelf * Hf[(size_t)node * M + ch + c];

    for (int base = 0; base < deg; base += 64) {
        int mySrc = (base + lane < deg) ? csr[e0 + base + lane] : 0;
        int lim = min(64, deg - base);
        for (int j = 0; j < lim; ++j) {
            int s = __shfl(mySrc, j);
            float al = expf(lrelu(asb[s * H + myh] + aa) - mm) * ii;
#pragma unroll
            for (int c = 0; c < CPL; ++c) acc[c] += al * Hf[(size_t)s * M + ch + c];
        }
    }

    if (active) {
#pragma unroll
        for (int c = 0; c < CPL; ++c)
            out[(size_t)node * M + ch + c] = elu(acc[c] + bias[ch + c]);
    }
}

// ---------------- mean pool ----------------
__global__ void pool_sum(const float* __restrict__ act, const int* __restrict__ batch,
                         float* __restrict__ out, float* __restrict__ cnt, int nNodes) {
    int idx = blockIdx.x * THREADS + threadIdx.x;
    if (idx >= nNodes * 32) return;
    int n = idx >> 5, c = idx & 31;
    int g = batch[n];
    atomicAdd(&out[g * 32 + c], act[(size_t)n * 32 + c]);
    if (c == 0) atomicAdd(&cnt[g], 1.0f);
}

__global__ void pool_div(float* __restrict__ out, const float* __restrict__ cnt, int G) {
    int idx = blockIdx.x * THREADS + threadIdx.x;
    if (idx >= G * 32) return;
    out[idx] /= fmaxf(cnt[idx >> 5], 1.0f);
}

// ---------------- host-side layer driver ----------------
template <int K, int M, int H, int C>
static void run_layer(const float* X, const float* W, const float* a_s, const float* a_d,
                      const float* bias, float* Hbuf, float* Out, float* asb, float* adb,
                      const int* rowptr, const int* csr, int N, hipStream_t stream) {
    gemm_kernel<K, M><<<(N + 15) / 16, THREADS, 0, stream>>>(X, W, Hbuf, N);
    alpha_kernel<M, H, C><<<(N * H + THREADS - 1) / THREADS, THREADS, 0, stream>>>(
        Hbuf, a_s, a_d, asb, adb, N);
    node_aggr<M, H, C><<<(N + 3) / 4, THREADS, 0, stream>>>(Hbuf, asb, adb, rowptr, csr, bias,
                                                            Out, N);
}

extern "C" void kernel_launch(void* const* d_in, const int* in_sizes, int n_in, void* d_out,
                              int out_size, void* d_ws, size_t ws_size, hipStream_t stream) {
    const float* x = (const float*)d_in[0];
    const int* ei = (const int*)d_in[1];
    const int* batch = (const int*)d_in[2];
    const float* W1 = (const float*)d_in[3];
    const float* as1 = (const float*)d_in[4];
    const float* ad1 = (const float*)d_in[5];
    const float* b1 = (const float*)d_in[6];
    const float* W2 = (const float*)d_in[7];
    const float* as2 = (const float*)d_in[8];
    const float* ad2 = (const float*)d_in[9];
    const float* b2 = (const float*)d_in[10];
    const float* W3 = (const float*)d_in[11];
    const float* as3 = (const float*)d_in[12];
    const float* ad3 = (const float*)d_in[13];
    const float* b3 = (const float*)d_in[14];

    const int N = in_sizes[0] / 128;
    const int E = in_sizes[1] / 2;
    const int G = out_size / 32;
    const int* srcp = ei;
    const int* dstp = ei + E;

    char* ws = (char*)d_ws;
    float* A = (float*)ws;                      // N*128
    float* B = A + (size_t)N * 128;             // N*128
    float* asb = B + (size_t)N * 128;           // N*4
    float* adb = asb + (size_t)N * 4;           // N*4
    float* cnt = adb + (size_t)N * 4;           // G
    int* rowptr = (int*)(cnt + G);              // N+1
    int* deg = rowptr + (N + 1);                // N
    int* cursor = deg + N;                      // N
    int* partial = cursor + N;                  // N
    int* bsum = partial + N;                    // THREADS
    int* csr = bsum + THREADS;                  // E

    const int nblk = (N + THREADS - 1) / THREADS;

    hipMemsetAsync(d_out, 0, (size_t)G * 32 * 4, stream);
    hipMemsetAsync(cnt, 0, (size_t)G * 4, stream);
    hipMemsetAsync(deg, 0, (size_t)N * 4, stream);

    // ---- CSR build (dst-sorted adjacency), once per call ----
    hist_kernel<<<(E + THREADS - 1) / THREADS, THREADS, 0, stream>>>(dstp, deg, E);
    scan1_kernel<<<nblk, THREADS, 0, stream>>>(deg, partial, bsum, N);
    scan2_kernel<<<1, THREADS, 0, stream>>>(bsum, nblk);
    scan3_kernel<<<nblk, THREADS, 0, stream>>>(partial, bsum, rowptr, cursor, N);
    scatter_kernel<<<(E + THREADS - 1) / THREADS, THREADS, 0, stream>>>(srcp, dstp, rowptr,
                                                                        cursor, csr, E);

    // Layer 1: x[N,128] -> B[N,128]
    run_layer<128, 128, 4, 32>(x, W1, as1, ad1, b1, A, B, asb, adb, rowptr, csr, N, stream);
    // Layer 2: B[N,128] -> B[N,128]
    run_layer<128, 128, 4, 32>(B, W2, as2, ad2, b2, A, B, asb, adb, rowptr, csr, N, stream);
    // Layer 3: B[N,128] -> B[N,32]
    run_layer<128, 32, 1, 32>(B, W3, as3, ad3, b3, A, B, asb, adb, rowptr, csr, N, stream);

    pool_sum<<<(N * 32 + THREADS - 1) / THREADS, THREADS, 0, stream>>>(B, batch, (float*)d_out,
                                                                       cnt, N);
    pool_div<<<(G * 32 + THREADS - 1) / THREADS, THREADS, 0, stream>>>((float*)d_out, cnt, G);
}

// Round 3
// 474.168 us; speedup vs baseline: 3.6586x; 1.1840x over previous
//
#include <hip/hip_runtime.h>

#define THREADS 256

__device__ __forceinline__ float lrelu(float x) { return x > 0.f ? x : 0.2f * x; }
__device__ __forceinline__ float elu(float x) { return x > 0.f ? x : expm1f(x); }

// ---------------- GEMM: Hout[N,M] = X[N,K] @ W[K,M] ----------------
template <int K, int M>
__global__ void gemm_kernel(const float* __restrict__ X, const float* __restrict__ W,
                            float* __restrict__ Hout, int nNodes) {
    constexpr int NB = 16;                 // nodes per block
    constexpr int NL = THREADS / M;        // node lanes
    constexpr int PER = NB / NL;           // nodes per thread
    __shared__ float xs[NB][K];

    int node0 = blockIdx.x * NB;
    for (int i = threadIdx.x; i < NB * K; i += THREADS) {
        int nn = i / K, kk = i % K;
        int n = node0 + nn;
        xs[nn][kk] = (n < nNodes) ? X[(size_t)n * K + kk] : 0.f;
    }
    __syncthreads();

    int col = threadIdx.x % M;
    int nl = threadIdx.x / M;
    float acc[PER];
#pragma unroll
    for (int i = 0; i < PER; ++i) acc[i] = 0.f;

    for (int k = 0; k < K; ++k) {
        float w = W[k * M + col];
#pragma unroll
        for (int i = 0; i < PER; ++i) acc[i] += xs[nl + i * NL][k] * w;
    }
#pragma unroll
    for (int i = 0; i < PER; ++i) {
        int n = node0 + nl + i * NL;
        if (n < nNodes) Hout[(size_t)n * M + col] = acc[i];
    }
}

// ---------------- per-node attention logits ----------------
template <int M, int H, int C>
__global__ void alpha_kernel(const float* __restrict__ Hf, const float* __restrict__ a_src,
                             const float* __restrict__ a_dst, float* __restrict__ asb,
                             float* __restrict__ adb, int nNodes) {
    int idx = blockIdx.x * THREADS + threadIdx.x;
    if (idx >= nNodes * H) return;
    int n = idx / H, h = idx % H;
    const float* hp = Hf + (size_t)n * M + h * C;
    float s = 0.f, d = 0.f;
#pragma unroll
    for (int c = 0; c < C; ++c) {
        float v = hp[c];
        s += v * a_src[h * C + c];
        d += v * a_dst[h * C + c];
    }
    asb[idx] = s;
    adb[idx] = d;
}

// ---------------- CSR build ----------------
__global__ void hist_kernel(const int* __restrict__ dst, int* __restrict__ deg, int nE) {
    int e = blockIdx.x * THREADS + threadIdx.x;
    if (e < nE) atomicAdd(&deg[dst[e]], 1);
}

__global__ void scan1_kernel(const int* __restrict__ deg, int* __restrict__ partial,
                             int* __restrict__ bsum, int n) {
    __shared__ int sh[THREADS];
    int i = blockIdx.x * THREADS + threadIdx.x;
    int v = (i < n) ? deg[i] : 0;
    sh[threadIdx.x] = v;
    __syncthreads();
    for (int off = 1; off < THREADS; off <<= 1) {
        int t = (threadIdx.x >= off) ? sh[threadIdx.x - off] : 0;
        __syncthreads();
        sh[threadIdx.x] += t;
        __syncthreads();
    }
    if (i < n) partial[i] = sh[threadIdx.x];  // inclusive scan within block
    if (threadIdx.x == THREADS - 1) bsum[blockIdx.x] = sh[THREADS - 1];
}

__global__ void scan2_kernel(int* __restrict__ bsum, int nblk) {
    __shared__ int sh[THREADS];
    int v = (threadIdx.x < nblk) ? bsum[threadIdx.x] : 0;
    sh[threadIdx.x] = v;
    __syncthreads();
    for (int off = 1; off < THREADS; off <<= 1) {
        int t = (threadIdx.x >= off) ? sh[threadIdx.x - off] : 0;
        __syncthreads();
        sh[threadIdx.x] += t;
        __syncthreads();
    }
    if (threadIdx.x < nblk)
        bsum[threadIdx.x] = (threadIdx.x == 0) ? 0 : sh[threadIdx.x - 1];  // exclusive
}

__global__ void scan3_kernel(const int* __restrict__ partial, const int* __restrict__ bsum,
                             int* __restrict__ rowptr, int* __restrict__ cursor, int n) {
    int i = blockIdx.x * THREADS + threadIdx.x;
    if (i < n) {
        rowptr[i + 1] = partial[i] + bsum[blockIdx.x];
        cursor[i] = 0;
    }
    if (i == 0) rowptr[0] = 0;
}

__global__ void scatter_kernel(const int* __restrict__ src, const int* __restrict__ dst,
                               const int* __restrict__ rowptr, int* __restrict__ cursor,
                               int* __restrict__ csr, int nE) {
    int e = blockIdx.x * THREADS + threadIdx.x;
    if (e >= nE) return;
    int d = dst[e];
    int p = atomicAdd(&cursor[d], 1);
    csr[rowptr[d] + p] = src[e];
}

// ---------------- helper: load H logits for source s ----------------
template <int H>
__device__ __forceinline__ void load_t(const float* __restrict__ asb, int s, bool valid,
                                       const float* adn, float* t) {
    if constexpr (H == 4) {
        float4 a4 = reinterpret_cast<const float4*>(asb)[s];
        float v[4] = {a4.x, a4.y, a4.z, a4.w};
#pragma unroll
        for (int h = 0; h < 4; ++h) t[h] = valid ? lrelu(v[h] + adn[h]) : -3.0e38f;
    } else {
        t[0] = valid ? lrelu(asb[s] + adn[0]) : -3.0e38f;
    }
}

// ---------------- fused per-node softmax + aggregation + ELU ----------------
// one wave per node; alpha precomputed lane-parallel into LDS; serial gather
// loop unrolled x8 with zero-padded alpha
template <int M, int H, int C>
__global__ void node_aggr(const float* __restrict__ Hf, const float* __restrict__ asb,
                          const float* __restrict__ adb, const int* __restrict__ rowptr,
                          const int* __restrict__ csr, const float* __restrict__ bias,
                          float* __restrict__ out, int nNodes) {
    constexpr int CPL = (M + 63) / 64;  // channels per lane
    constexpr int WPB = THREADS / 64;   // waves per block
    __shared__ __align__(16) float al_sh[WPB][64 * H];
    __shared__ int off_sh[WPB][64];

    const int wid = threadIdx.x >> 6;
    const int lane = threadIdx.x & 63;
    const int node = blockIdx.x * WPB + wid;
    if (node >= nNodes) return;

    const int e0 = rowptr[node];
    const int deg = rowptr[node + 1] - e0;

    float adn[H], eself[H];
    if constexpr (H == 4) {
        float4 ad4 = reinterpret_cast<const float4*>(adb)[node];
        float4 as4 = reinterpret_cast<const float4*>(asb)[node];
        adn[0] = ad4.x; adn[1] = ad4.y; adn[2] = ad4.z; adn[3] = ad4.w;
        eself[0] = lrelu(as4.x + adn[0]);
        eself[1] = lrelu(as4.y + adn[1]);
        eself[2] = lrelu(as4.z + adn[2]);
        eself[3] = lrelu(as4.w + adn[3]);
    } else {
        adn[0] = adb[node];
        eself[0] = lrelu(asb[node] + adn[0]);
    }

    float m[H], inv[H];
    const bool fast = (deg <= 64);

    if (fast) {
        const bool valid = lane < deg;
        const int s = valid ? csr[e0 + lane] : node;
        float t[H];
        load_t<H>(asb, s, valid, adn, t);
#pragma unroll
        for (int h = 0; h < H; ++h) m[h] = t[h];
#pragma unroll
        for (int off = 32; off > 0; off >>= 1)
#pragma unroll
            for (int h = 0; h < H; ++h) m[h] = fmaxf(m[h], __shfl_xor(m[h], off));
#pragma unroll
        for (int h = 0; h < H; ++h) m[h] = fmaxf(m[h], eself[h]);

        float den[H];
        float ex[H];
#pragma unroll
        for (int h = 0; h < H; ++h) { ex[h] = __expf(t[h] - m[h]); den[h] = ex[h]; }
#pragma unroll
        for (int off = 32; off > 0; off >>= 1)
#pragma unroll
            for (int h = 0; h < H; ++h) den[h] += __shfl_xor(den[h], off);
#pragma unroll
        for (int h = 0; h < H; ++h) {
            den[h] += __expf(eself[h] - m[h]);
            inv[h] = 1.f / (den[h] + 1e-16f);
        }
        if constexpr (H == 4) {
            float4 w = make_float4(ex[0] * inv[0], ex[1] * inv[1], ex[2] * inv[2],
                                   ex[3] * inv[3]);
            *reinterpret_cast<float4*>(&al_sh[wid][lane * 4]) = w;
        } else {
            al_sh[wid][lane] = ex[0] * inv[0];
        }
        off_sh[wid][lane] = s * M;
    } else {
        // fallback: 2-pass stats for deg > 64
#pragma unroll
        for (int h = 0; h < H; ++h) m[h] = eself[h];
        for (int base = 0; base < deg; base += 64) {
            bool valid = base + lane < deg;
            int s = valid ? csr[e0 + base + lane] : node;
            float t[H];
            load_t<H>(asb, s, valid, adn, t);
#pragma unroll
            for (int h = 0; h < H; ++h) m[h] = fmaxf(m[h], t[h]);
        }
#pragma unroll
        for (int off = 32; off > 0; off >>= 1)
#pragma unroll
            for (int h = 0; h < H; ++h) m[h] = fmaxf(m[h], __shfl_xor(m[h], off));

        float den[H];
#pragma unroll
        for (int h = 0; h < H; ++h) den[h] = 0.f;
        for (int base = 0; base < deg; base += 64) {
            bool valid = base + lane < deg;
            int s = valid ? csr[e0 + base + lane] : node;
            float t[H];
            load_t<H>(asb, s, valid, adn, t);
#pragma unroll
            for (int h = 0; h < H; ++h) den[h] += __expf(t[h] - m[h]);
        }
#pragma unroll
        for (int off = 32; off > 0; off >>= 1)
#pragma unroll
            for (int h = 0; h < H; ++h) den[h] += __shfl_xor(den[h], off);
#pragma unroll
        for (int h = 0; h < H; ++h) {
            den[h] += __expf(eself[h] - m[h]);
            inv[h] = 1.f / (den[h] + 1e-16f);
        }
    }

    // ---- accumulate ----
    int ch = lane * CPL;
    const bool active = ch < M;
    if (ch > M - CPL) ch = M - CPL;
    const int myh = ch / C;

    float mm = m[0], ii = inv[0], es = eself[0];
#pragma unroll
    for (int h = 1; h < H; ++h)
        if (myh == h) { mm = m[h]; ii = inv[h]; es = eself[h]; }

    float acc[CPL];
    const float alSelf = __expf(es - mm) * ii;
#pragma unroll
    for (int c = 0; c < CPL; ++c) acc[c] = alSelf * Hf[(size_t)node * M + ch + c];

    auto serial = [&](int cnt) {
        for (int j0 = 0; j0 < cnt; j0 += 8) {
#pragma unroll
            for (int jj = 0; jj < 8; ++jj) {
                int j = j0 + jj;
                int wo = off_sh[wid][j];
                float al = al_sh[wid][j * H + myh];
                const float* p = Hf + wo + ch;
#pragma unroll
                for (int c = 0; c < CPL; ++c) acc[c] += al * p[c];
            }
        }
    };

    if (fast) {
        serial((deg + 7) & ~7);
    } else {
        for (int base = 0; base < deg; base += 64) {
            bool valid = base + lane < deg;
            int s = valid ? csr[e0 + base + lane] : node;
            float t[H];
            load_t<H>(asb, s, valid, adn, t);
            if constexpr (H == 4) {
                float4 w = make_float4(__expf(t[0] - m[0]) * inv[0],
                                       __expf(t[1] - m[1]) * inv[1],
                                       __expf(t[2] - m[2]) * inv[2],
                                       __expf(t[3] - m[3]) * inv[3]);
                *reinterpret_cast<float4*>(&al_sh[wid][lane * 4]) = w;
            } else {
                al_sh[wid][lane] = __expf(t[0] - m[0]) * inv[0];
            }
            off_sh[wid][lane] = s * M;
            int cl = deg - base;
            if (cl > 64) cl = 64;
            serial((cl + 7) & ~7);
        }
    }

    if (active) {
#pragma unroll
        for (int c = 0; c < CPL; ++c)
            out[(size_t)node * M + ch + c] = elu(acc[c] + bias[ch + c]);
    }
}

// ---------------- mean pool ----------------
__global__ void pool_sum(const float* __restrict__ act, const int* __restrict__ batch,
                         float* __restrict__ out, float* __restrict__ cnt, int nNodes) {
    int idx = blockIdx.x * THREADS + threadIdx.x;
    if (idx >= nNodes * 32) return;
    int n = idx >> 5, c = idx & 31;
    int g = batch[n];
    atomicAdd(&out[g * 32 + c], act[(size_t)n * 32 + c]);
    if (c == 0) atomicAdd(&cnt[g], 1.0f);
}

__global__ void pool_div(float* __restrict__ out, const float* __restrict__ cnt, int G) {
    int idx = blockIdx.x * THREADS + threadIdx.x;
    if (idx >= G * 32) return;
    out[idx] /= fmaxf(cnt[idx >> 5], 1.0f);
}

// ---------------- host-side layer driver ----------------
template <int K, int M, int H, int C>
static void run_layer(const float* X, const float* W, const float* a_s, const float* a_d,
                      const float* bias, float* Hbuf, float* Out, float* asb, float* adb,
                      const int* rowptr, const int* csr, int N, hipStream_t stream) {
    gemm_kernel<K, M><<<(N + 15) / 16, THREADS, 0, stream>>>(X, W, Hbuf, N);
    alpha_kernel<M, H, C><<<(N * H + THREADS - 1) / THREADS, THREADS, 0, stream>>>(
        Hbuf, a_s, a_d, asb, adb, N);
    node_aggr<M, H, C><<<(N + 3) / 4, THREADS, 0, stream>>>(Hbuf, asb, adb, rowptr, csr, bias,
                                                            Out, N);
}

extern "C" void kernel_launch(void* const* d_in, const int* in_sizes, int n_in, void* d_out,
                              int out_size, void* d_ws, size_t ws_size, hipStream_t stream) {
    const float* x = (const float*)d_in[0];
    const int* ei = (const int*)d_in[1];
    const int* batch = (const int*)d_in[2];
    const float* W1 = (const float*)d_in[3];
    const float* as1 = (const float*)d_in[4];
    const float* ad1 = (const float*)d_in[5];
    const float* b1 = (const float*)d_in[6];
    const float* W2 = (const float*)d_in[7];
    const float* as2 = (const float*)d_in[8];
    const float* ad2 = (const float*)d_in[9];
    const float* b2 = (const float*)d_in[10];
    const float* W3 = (const float*)d_in[11];
    const float* as3 = (const float*)d_in[12];
    const float* ad3 = (const float*)d_in[13];
    const float* b3 = (const float*)d_in[14];

    const int N = in_sizes[0] / 128;
    const int E = in_sizes[1] / 2;
    const int G = out_size / 32;
    const int* srcp = ei;
    const int* dstp = ei + E;

    char* ws = (char*)d_ws;
    float* A = (float*)ws;                      // N*128
    float* B = A + (size_t)N * 128;             // N*128
    float* asb = B + (size_t)N * 128;           // N*4
    float* adb = asb + (size_t)N * 4;           // N*4
    float* cnt = adb + (size_t)N * 4;           // G
    int* rowptr = (int*)(cnt + G);              // N+1
    int* deg = rowptr + (N + 1);                // N
    int* cursor = deg + N;                      // N
    int* partial = cursor + N;                  // N
    int* bsum = partial + N;                    // THREADS
    int* csr = bsum + THREADS;                  // E

    const int nblk = (N + THREADS - 1) / THREADS;

    hipMemsetAsync(d_out, 0, (size_t)G * 32 * 4, stream);
    hipMemsetAsync(cnt, 0, (size_t)G * 4, stream);
    hipMemsetAsync(deg, 0, (size_t)N * 4, stream);

    // ---- CSR build (dst-sorted adjacency), once per call ----
    hist_kernel<<<(E + THREADS - 1) / THREADS, THREADS, 0, stream>>>(dstp, deg, E);
    scan1_kernel<<<nblk, THREADS, 0, stream>>>(deg, partial, bsum, N);
    scan2_kernel<<<1, THREADS, 0, stream>>>(bsum, nblk);
    scan3_kernel<<<nblk, THREADS, 0, stream>>>(partial, bsum, rowptr, cursor, N);
    scatter_kernel<<<(E + THREADS - 1) / THREADS, THREADS, 0, stream>>>(srcp, dstp, rowptr,
                                                                        cursor, csr, E);

    // Layer 1: x[N,128] -> B[N,128]
    run_layer<128, 128, 4, 32>(x, W1, as1, ad1, b1, A, B, asb, adb, rowptr, csr, N, stream);
    // Layer 2: B[N,128] -> B[N,128]
    run_layer<128, 128, 4, 32>(B, W2, as2, ad2, b2, A, B, asb, adb, rowptr, csr, N, stream);
    // Layer 3: B[N,128] -> B[N,32]
    run_layer<128, 32, 1, 32>(B, W3, as3, ad3, b3, A, B, asb, adb, rowptr, csr, N, stream);

    pool_sum<<<(N * 32 + THREADS - 1) / THREADS, THREADS, 0, stream>>>(B, batch, (float*)d_out,
                                                                       cnt, N);
    pool_div<<<(G * 32 + THREADS - 1) / THREADS, THREADS, 0, stream>>>((float*)d_out, cnt, G);
}

// Round 4
// 412.790 us; speedup vs baseline: 4.2026x; 1.1487x over previous
//
#include <hip/hip_runtime.h>

#define THREADS 256

__device__ __forceinline__ float lrelu(float x) { return x > 0.f ? x : 0.2f * x; }
__device__ __forceinline__ float elu(float x) { return x > 0.f ? x : expm1f(x); }

// ---------------- GEMM: Hout[N,M] = X[N,K] @ W[K,M] ----------------
template <int K, int M>
__global__ void gemm_kernel(const float* __restrict__ X, const float* __restrict__ W,
                            float* __restrict__ Hout, int nNodes) {
    constexpr int NB = 16;                 // nodes per block
    constexpr int NL = THREADS / M;        // node lanes
    constexpr int PER = NB / NL;           // nodes per thread
    __shared__ float xs[NB][K];

    int node0 = blockIdx.x * NB;
    for (int i = threadIdx.x; i < NB * K; i += THREADS) {
        int nn = i / K, kk = i % K;
        int n = node0 + nn;
        xs[nn][kk] = (n < nNodes) ? X[(size_t)n * K + kk] : 0.f;
    }
    __syncthreads();

    int col = threadIdx.x % M;
    int nl = threadIdx.x / M;
    float acc[PER];
#pragma unroll
    for (int i = 0; i < PER; ++i) acc[i] = 0.f;

    for (int k = 0; k < K; ++k) {
        float w = W[k * M + col];
#pragma unroll
        for (int i = 0; i < PER; ++i) acc[i] += xs[nl + i * NL][k] * w;
    }
#pragma unroll
    for (int i = 0; i < PER; ++i) {
        int n = node0 + nl + i * NL;
        if (n < nNodes) Hout[(size_t)n * M + col] = acc[i];
    }
}

// ---------------- per-node attention logits ----------------
template <int M, int H, int C>
__global__ void alpha_kernel(const float* __restrict__ Hf, const float* __restrict__ a_src,
                             const float* __restrict__ a_dst, float* __restrict__ asb,
                             float* __restrict__ adb, int nNodes) {
    int idx = blockIdx.x * THREADS + threadIdx.x;
    if (idx >= nNodes * H) return;
    int n = idx / H, h = idx % H;
    const float* hp = Hf + (size_t)n * M + h * C;
    float s = 0.f, d = 0.f;
#pragma unroll
    for (int c = 0; c < C; ++c) {
        float v = hp[c];
        s += v * a_src[h * C + c];
        d += v * a_dst[h * C + c];
    }
    asb[idx] = s;
    adb[idx] = d;
}

// ---------------- CSR build ----------------
__global__ void hist_kernel(const int* __restrict__ dst, int* __restrict__ deg, int nE) {
    int e = blockIdx.x * THREADS + threadIdx.x;
    if (e < nE) atomicAdd(&deg[dst[e]], 1);
}

__global__ void scan1_kernel(const int* __restrict__ deg, int* __restrict__ partial,
                             int* __restrict__ bsum, int n) {
    __shared__ int sh[THREADS];
    int i = blockIdx.x * THREADS + threadIdx.x;
    int v = (i < n) ? deg[i] : 0;
    sh[threadIdx.x] = v;
    __syncthreads();
    for (int off = 1; off < THREADS; off <<= 1) {
        int t = (threadIdx.x >= off) ? sh[threadIdx.x - off] : 0;
        __syncthreads();
        sh[threadIdx.x] += t;
        __syncthreads();
    }
    if (i < n) partial[i] = sh[threadIdx.x];  // inclusive scan within block
    if (threadIdx.x == THREADS - 1) bsum[blockIdx.x] = sh[THREADS - 1];
}

__global__ void scan2_kernel(int* __restrict__ bsum, int nblk) {
    __shared__ int sh[THREADS];
    int v = (threadIdx.x < nblk) ? bsum[threadIdx.x] : 0;
    sh[threadIdx.x] = v;
    __syncthreads();
    for (int off = 1; off < THREADS; off <<= 1) {
        int t = (threadIdx.x >= off) ? sh[threadIdx.x - off] : 0;
        __syncthreads();
        sh[threadIdx.x] += t;
        __syncthreads();
    }
    if (threadIdx.x < nblk)
        bsum[threadIdx.x] = (threadIdx.x == 0) ? 0 : sh[threadIdx.x - 1];  // exclusive
}

__global__ void scan3_kernel(const int* __restrict__ partial, const int* __restrict__ bsum,
                             int* __restrict__ rowptr, int* __restrict__ cursor, int n) {
    int i = blockIdx.x * THREADS + threadIdx.x;
    if (i < n) {
        rowptr[i + 1] = partial[i] + bsum[blockIdx.x];
        cursor[i] = 0;
    }
    if (i == 0) rowptr[0] = 0;
}

__global__ void scatter_kernel(const int* __restrict__ src, const int* __restrict__ dst,
                               const int* __restrict__ rowptr, int* __restrict__ cursor,
                               int* __restrict__ csr, int nE) {
    int e = blockIdx.x * THREADS + threadIdx.x;
    if (e >= nE) return;
    int d = dst[e];
    int p = atomicAdd(&cursor[d], 1);
    csr[rowptr[d] + p] = src[e];
}

// ---------------- helper: load H logits for source s ----------------
template <int H>
__device__ __forceinline__ void load_t(const float* __restrict__ asb, int s, bool valid,
                                       const float* adn, float* t) {
    if constexpr (H == 4) {
        float4 a4 = reinterpret_cast<const float4*>(asb)[s];
        float v[4] = {a4.x, a4.y, a4.z, a4.w};
#pragma unroll
        for (int h = 0; h < 4; ++h) t[h] = valid ? lrelu(v[h] + adn[h]) : -3.0e38f;
    } else {
        t[0] = valid ? lrelu(asb[s] + adn[0]) : -3.0e38f;
    }
}

// ---------------- fused per-node softmax + aggregation + ELU ----------------
template <int M, int H, int C>
__global__ void node_aggr(const float* __restrict__ Hf, const float* __restrict__ asb,
                          const float* __restrict__ adb, const int* __restrict__ rowptr,
                          const int* __restrict__ csr, const float* __restrict__ bias,
                          float* __restrict__ out, int nNodes) {
    constexpr int CPL = (M + 63) / 64;  // channels per lane
    constexpr int WPB = THREADS / 64;   // waves per block
    __shared__ __align__(16) float al_sh[WPB][64 * H];
    __shared__ int off_sh[WPB][64];

    const int wid = threadIdx.x >> 6;
    const int lane = threadIdx.x & 63;
    const int node = blockIdx.x * WPB + wid;
    if (node >= nNodes) return;

    const int e0 = rowptr[node];
    const int deg = rowptr[node + 1] - e0;

    float adn[H], eself[H];
    if constexpr (H == 4) {
        float4 ad4 = reinterpret_cast<const float4*>(adb)[node];
        float4 as4 = reinterpret_cast<const float4*>(asb)[node];
        adn[0] = ad4.x; adn[1] = ad4.y; adn[2] = ad4.z; adn[3] = ad4.w;
        eself[0] = lrelu(as4.x + adn[0]);
        eself[1] = lrelu(as4.y + adn[1]);
        eself[2] = lrelu(as4.z + adn[2]);
        eself[3] = lrelu(as4.w + adn[3]);
    } else {
        adn[0] = adb[node];
        eself[0] = lrelu(asb[node] + adn[0]);
    }

    float m[H], inv[H];
    const bool fast = (deg <= 64);

    if (fast) {
        const bool valid = lane < deg;
        const int s = valid ? csr[e0 + lane] : node;
        float t[H];
        load_t<H>(asb, s, valid, adn, t);
#pragma unroll
        for (int h = 0; h < H; ++h) m[h] = t[h];
#pragma unroll
        for (int off = 32; off > 0; off >>= 1)
#pragma unroll
            for (int h = 0; h < H; ++h) m[h] = fmaxf(m[h], __shfl_xor(m[h], off));
#pragma unroll
        for (int h = 0; h < H; ++h) m[h] = fmaxf(m[h], eself[h]);

        float den[H];
        float ex[H];
#pragma unroll
        for (int h = 0; h < H; ++h) { ex[h] = __expf(t[h] - m[h]); den[h] = ex[h]; }
#pragma unroll
        for (int off = 32; off > 0; off >>= 1)
#pragma unroll
            for (int h = 0; h < H; ++h) den[h] += __shfl_xor(den[h], off);
#pragma unroll
        for (int h = 0; h < H; ++h) {
            den[h] += __expf(eself[h] - m[h]);
            inv[h] = 1.f / (den[h] + 1e-16f);
        }
        if constexpr (H == 4) {
            float4 w = make_float4(ex[0] * inv[0], ex[1] * inv[1], ex[2] * inv[2],
                                   ex[3] * inv[3]);
            *reinterpret_cast<float4*>(&al_sh[wid][lane * 4]) = w;
        } else {
            al_sh[wid][lane] = ex[0] * inv[0];
        }
        off_sh[wid][lane] = s * M;
    } else {
        // fallback: 2-pass stats for deg > 64
#pragma unroll
        for (int h = 0; h < H; ++h) m[h] = eself[h];
        for (int base = 0; base < deg; base += 64) {
            bool valid = base + lane < deg;
            int s = valid ? csr[e0 + base + lane] : node;
            float t[H];
            load_t<H>(asb, s, valid, adn, t);
#pragma unroll
            for (int h = 0; h < H; ++h) m[h] = fmaxf(m[h], t[h]);
        }
#pragma unroll
        for (int off = 32; off > 0; off >>= 1)
#pragma unroll
            for (int h = 0; h < H; ++h) m[h] = fmaxf(m[h], __shfl_xor(m[h], off));

        float den[H];
#pragma unroll
        for (int h = 0; h < H; ++h) den[h] = 0.f;
        for (int base = 0; base < deg; base += 64) {
            bool valid = base + lane < deg;
            int s = valid ? csr[e0 + base + lane] : node;
            float t[H];
            load_t<H>(asb, s, valid, adn, t);
#pragma unroll
            for (int h = 0; h < H; ++h) den[h] += __expf(t[h] - m[h]);
        }
#pragma unroll
        for (int off = 32; off > 0; off >>= 1)
#pragma unroll
            for (int h = 0; h < H; ++h) den[h] += __shfl_xor(den[h], off);
#pragma unroll
        for (int h = 0; h < H; ++h) {
            den[h] += __expf(eself[h] - m[h]);
            inv[h] = 1.f / (den[h] + 1e-16f);
        }
    }

    // ---- accumulate ----
    int ch = lane * CPL;
    const bool active = ch < M;
    if (ch > M - CPL) ch = M - CPL;
    const int myh = ch / C;

    float mm = m[0], ii = inv[0], es = eself[0];
#pragma unroll
    for (int h = 1; h < H; ++h)
        if (myh == h) { mm = m[h]; ii = inv[h]; es = eself[h]; }

    float acc[CPL];
    const float alSelf = __expf(es - mm) * ii;
#pragma unroll
    for (int c = 0; c < CPL; ++c) acc[c] = alSelf * Hf[(size_t)node * M + ch + c];

    auto serial = [&](int cnt) {
        for (int j0 = 0; j0 < cnt; j0 += 8) {
#pragma unroll
            for (int jj = 0; jj < 8; ++jj) {
                int j = j0 + jj;
                int wo = off_sh[wid][j];
                float al = al_sh[wid][j * H + myh];
                const float* p = Hf + wo + ch;
#pragma unroll
                for (int c = 0; c < CPL; ++c) acc[c] += al * p[c];
            }
        }
    };

    if (fast) {
        serial((deg + 7) & ~7);
    } else {
        for (int base = 0; base < deg; base += 64) {
            bool valid = base + lane < deg;
            int s = valid ? csr[e0 + base + lane] : node;
            float t[H];
            load_t<H>(asb, s, valid, adn, t);
            if constexpr (H == 4) {
                float4 w = make_float4(__expf(t[0] - m[0]) * inv[0],
                                       __expf(t[1] - m[1]) * inv[1],
                                       __expf(t[2] - m[2]) * inv[2],
                                       __expf(t[3] - m[3]) * inv[3]);
                *reinterpret_cast<float4*>(&al_sh[wid][lane * 4]) = w;
            } else {
                al_sh[wid][lane] = __expf(t[0] - m[0]) * inv[0];
            }
            off_sh[wid][lane] = s * M;
            int cl = deg - base;
            if (cl > 64) cl = 64;
            serial((cl + 7) & ~7);
        }
    }

    if (active) {
#pragma unroll
        for (int c = 0; c < CPL; ++c)
            out[(size_t)node * M + ch + c] = elu(acc[c] + bias[ch + c]);
    }
}

// ---------------- mean pool (sorted batch -> segmented reduction) ----------------
__global__ void group_bounds(const int* __restrict__ batch, int* __restrict__ gstart, int N,
                             int G) {
    int g = blockIdx.x * THREADS + threadIdx.x;
    if (g > G) return;
    int lo = 0, hi = N;
    while (lo < hi) {
        int mid = (lo + hi) >> 1;
        if (batch[mid] < g) lo = mid + 1;
        else hi = mid;
    }
    gstart[g] = lo;
}

__global__ void pool_kernel(const float* __restrict__ act, const int* __restrict__ gstart,
                            float* __restrict__ out, int G) {
    int wid = threadIdx.x >> 6;
    int lane = threadIdx.x & 63;
    int g = blockIdx.x * (THREADS / 64) + wid;
    if (g >= G) return;
    int s = gstart[g], e = gstart[g + 1];
    int c = lane & 31, half = lane >> 5;
    float acc = 0.f;
    for (int n = s + half; n < e; n += 2) acc += act[(size_t)n * 32 + c];
    acc += __shfl_xor(acc, 32);
    if (lane < 32) out[g * 32 + c] = acc / fmaxf((float)(e - s), 1.f);
}

// ---------------- host-side layer driver ----------------
template <int K, int M, int H, int C>
static void run_layer(const float* X, const float* W, const float* a_s, const float* a_d,
                      const float* bias, float* Hbuf, float* Out, float* asb, float* adb,
                      const int* rowptr, const int* csr, int N, hipStream_t stream) {
    gemm_kernel<K, M><<<(N + 15) / 16, THREADS, 0, stream>>>(X, W, Hbuf, N);
    alpha_kernel<M, H, C><<<(N * H + THREADS - 1) / THREADS, THREADS, 0, stream>>>(
        Hbuf, a_s, a_d, asb, adb, N);
    node_aggr<M, H, C><<<(N + 3) / 4, THREADS, 0, stream>>>(Hbuf, asb, adb, rowptr, csr, bias,
                                                            Out, N);
}

extern "C" void kernel_launch(void* const* d_in, const int* in_sizes, int n_in, void* d_out,
                              int out_size, void* d_ws, size_t ws_size, hipStream_t stream) {
    const float* x = (const float*)d_in[0];
    const int* ei = (const int*)d_in[1];
    const int* batch = (const int*)d_in[2];
    const float* W1 = (const float*)d_in[3];
    const float* as1 = (const float*)d_in[4];
    const float* ad1 = (const float*)d_in[5];
    const float* b1 = (const float*)d_in[6];
    const float* W2 = (const float*)d_in[7];
    const float* as2 = (const float*)d_in[8];
    const float* ad2 = (const float*)d_in[9];
    const float* b2 = (const float*)d_in[10];
    const float* W3 = (const float*)d_in[11];
    const float* as3 = (const float*)d_in[12];
    const float* ad3 = (const float*)d_in[13];
    const float* b3 = (const float*)d_in[14];

    const int N = in_sizes[0] / 128;
    const int E = in_sizes[1] / 2;
    const int G = out_size / 32;
    const int* srcp = ei;
    const int* dstp = ei + E;

    char* ws = (char*)d_ws;
    float* A = (float*)ws;                      // N*128
    float* B = A + (size_t)N * 128;             // N*128
    float* asb = B + (size_t)N * 128;           // N*4
    float* adb = asb + (size_t)N * 4;           // N*4
    int* gstart = (int*)(adb + (size_t)N * 4);  // G+1
    int* rowptr = gstart + (G + 1);             // N+1
    int* deg = rowptr + (N + 1);                // N
    int* cursor = deg + N;                      // N
    int* partial = cursor + N;                  // N
    int* bsum = partial + N;                    // THREADS
    int* csr = bsum + THREADS;                  // E

    const int nblk = (N + THREADS - 1) / THREADS;

    hipMemsetAsync(deg, 0, (size_t)N * 4, stream);

    // ---- CSR build (dst-sorted adjacency), once per call ----
    hist_kernel<<<(E + THREADS - 1) / THREADS, THREADS, 0, stream>>>(dstp, deg, E);
    scan1_kernel<<<nblk, THREADS, 0, stream>>>(deg, partial, bsum, N);
    scan2_kernel<<<1, THREADS, 0, stream>>>(bsum, nblk);
    scan3_kernel<<<nblk, THREADS, 0, stream>>>(partial, bsum, rowptr, cursor, N);
    scatter_kernel<<<(E + THREADS - 1) / THREADS, THREADS, 0, stream>>>(srcp, dstp, rowptr,
                                                                        cursor, csr, E);
    group_bounds<<<(G + 1 + THREADS - 1) / THREADS, THREADS, 0, stream>>>(batch, gstart, N, G);

    // Layer 1: x[N,128] -> B[N,128]
    run_layer<128, 128, 4, 32>(x, W1, as1, ad1, b1, A, B, asb, adb, rowptr, csr, N, stream);
    // Layer 2: B[N,128] -> B[N,128]
    run_layer<128, 128, 4, 32>(B, W2, as2, ad2, b2, A, B, asb, adb, rowptr, csr, N, stream);
    // Layer 3: B[N,128] -> B[N,32]
    run_layer<128, 32, 1, 32>(B, W3, as3, ad3, b3, A, B, asb, adb, rowptr, csr, N, stream);

    pool_kernel<<<(G + 3) / 4, THREADS, 0, stream>>>(B, gstart, (float*)d_out, G);
}